// Round 9
// baseline (180.301 us; speedup 1.0000x reference)
//
#include <hip/hip_runtime.h>

// Problem constants (match reference)
#define K_     1056
#define N_     2112
#define M_     1056   // N - K
#define E_     6336   // M * 6
#define NIE_   5280   // M * 5 info-side edges (the only BP state)
#define CAP_   6336   // padded c2v extent upper bound (stride = d|1 adds <=1/VN)
#define ALL_   7392   // CAP_ + K_ : c2v + marg unified array (float2 units)
#define DV_    5
#define ROW_   6      // edge 6m+5 is the parity VN K+m
#define NSYM_  528
#define NITER_ 20
#define BATCH_ 1024
#define BS_    1024   // 16 waves/block, 2 blocks/CU = 32 waves
#define KMAX_  2      // ceil(K_/BS_) work trips per thread
#define NCW_   2      // codewords per block (float2-packed payload)

#define LOG2E_ 1.4426950408889634f
#define AVLO_  (1e-6f * LOG2E_)          // |v2c| floor, bits units
#define AVHI_  (20.0f * LOG2E_)          // |v2c| cap,  bits units
#define QC_    0.99999988f               // tanh-domain cap (unchanged)

// ext_vector pair type -> backend emits v_pk_add_f32/v_pk_mul_f32
// (two independent IEEE fp32 lanes per instruction; per-component
// rounding identical to scalar -> bit-exact vs scalar form). [R27]
typedef float f2 __attribute__((ext_vector_type(2)));

// stride(d) = d | 1 : always ODD -> coprime with the 16 bank-pairs of a
// b64 access -> Phase A's wave-uniform-stride segment reads stay
// conflict-free in the float2 layout.
__device__ __forceinline__ int seg_stride(int d) { return d | 1; }

// Bare-instruction transcendentals (R17 win: OCML wrappers inflated the
// hot loop ~2x; inputs always normal-range, <=1 ULP deviation validated
// absmax-0 since R1).
__device__ __forceinline__ float fexp2(float x) { return __builtin_amdgcn_exp2f(x); }
__device__ __forceinline__ float flog2(float x) { return __builtin_amdgcn_logf(x); }
__device__ __forceinline__ float frcp(float x)  { return __builtin_amdgcn_rcpf(x); }

// R28: degree-specialized marginal accumulate. Slots are degree-sorted,
// so dg is wave-uniform; unrolled cases give one base address +
// ds_read2_b64 immediate-offset pairs instead of per-pair loop control.
// Add order is ascending d — IDENTICAL fp sequence to the generic loop.
__device__ __forceinline__ f2 seg_acc(const f2* seg, int dg, f2 mg) {
#define AC_(i) mg = mg + seg[i];
    switch (dg) {
    case 0: break;
    case 1: AC_(0) break;
    case 2: AC_(0) AC_(1) break;
    case 3: AC_(0) AC_(1) AC_(2) break;
    case 4: AC_(0) AC_(1) AC_(2) AC_(3) break;
    case 5: AC_(0) AC_(1) AC_(2) AC_(3) AC_(4) break;
    case 6: AC_(0) AC_(1) AC_(2) AC_(3) AC_(4) AC_(5) break;
    case 7: AC_(0) AC_(1) AC_(2) AC_(3) AC_(4) AC_(5) AC_(6) break;
    case 8: AC_(0) AC_(1) AC_(2) AC_(3) AC_(4) AC_(5) AC_(6) AC_(7) break;
    case 9: AC_(0) AC_(1) AC_(2) AC_(3) AC_(4) AC_(5) AC_(6) AC_(7) AC_(8) break;
    case 10: AC_(0) AC_(1) AC_(2) AC_(3) AC_(4) AC_(5) AC_(6) AC_(7) AC_(8) AC_(9) break;
    case 11: AC_(0) AC_(1) AC_(2) AC_(3) AC_(4) AC_(5) AC_(6) AC_(7) AC_(8) AC_(9) AC_(10) break;
    case 12: AC_(0) AC_(1) AC_(2) AC_(3) AC_(4) AC_(5) AC_(6) AC_(7) AC_(8) AC_(9) AC_(10) AC_(11) break;
    default: {
        int d = 0;
        for (; d + 1 < dg; d += 2) { mg = mg + seg[d]; mg = mg + seg[d + 1]; }
        if (d < dg) mg = mg + seg[d];
    }
    }
#undef AC_
    return mg;
}

// -------------------------------------------------------------------------
// Single kernel, TWO codewords per block, 1024 threads / 16 waves.
// == R28: R27 (pk dual-codeword BP) + one-eval demap + degree-switch A ==
//
// R27 post-mortem: VALUBusy 71->63, 108.8us; VALU still the largest pipe
// (63% = ~164k cy/CU) but co-binding with LDS (73k incl 52k conflicts).
// R28 cuts the two remaining fat VALU blocks, both bit-exact:
//  (1) demap: the old per-bit two-pass form evaluated each point's
//      lg = -(d2)/no EIGHT times (4 bits x 2 passes), incl. 8 exact fp32
//      divisions/point. Now: one max-pass p-loop updating m0[4]/m1[4],
//      one sum-pass p-loop updating s0[4]/s1[4] -> 32 evals, 32 divs.
//      For each bit, fmax/sum sequences visit p ascending with identical
//      operands -> bit-identical LLRs (recomputation elision only).
//  (2) Phase A: degree-switch unrolled accumulate (see seg_acc) --
//      ascending add order preserved, ~2x fewer issue slots.
// R25/R27 spill (~57MB WRITE) confirmed one-shot prologue (95KB/block),
// latency-hidden; all de-spill attempts (R21/22/24/26) lost to it.
//
// LDS map (f2 units, s_all2[7392] = 59136 B):
//   [0..CAP)   build: [0..N) staging (VN i -> {llr_cw0, llr_cw1}),
//              [N..N+2112) = 4224 ints of build scratch;
//              BP: c2v odd-stride VN-major segments (r-values)
//   [CAP..ALL) slot-indexed marginals (f2)
//
// Structure: H = [A | I]; parity VN deg-1 -> per-check constant t5;
// degree-sorted slots (wave-uniform Phase A trips); scan-free bases from
// 32-bin histogram; od packs base|deg<<13|pv<<18; atomic build order
// only permutes accumulation order (validated order-independent R4-R27).
//
// CN math per component (prefix/suffix partial products, bits domain):
//   t = copysign((1-2^-av)/(1+2^-av), v2c);  q_j = t5 * prod_{i!=j} t_i
//   q = med3(q, -QC, QC);  r = log2((1+q)/(1-q))
// -------------------------------------------------------------------------
__global__ __launch_bounds__(BS_, 8) void link_kernel(
    const int*   __restrict__ bits,      // [B,K]
    const int*   __restrict__ a_idx,     // [M,DV]
    const float* __restrict__ points_re, // [16]
    const float* __restrict__ points_im, // [16]
    const float* __restrict__ noise_re,  // [B,NSYM]
    const float* __restrict__ noise_im,  // [B,NSYM]
    const float* __restrict__ ebno_db,   // [1]
    const int*   __restrict__ edge_vn,   // [E]
    float*       __restrict__ out)       // [2,B,K]
{
#pragma clang fp contract(off)
    const int blk = blockIdx.x;
    const int b0  = blk * NCW_;          // codeword 0 (component .x)
    const int b1  = b0 + 1;              // codeword 1 (component .y)
    const int tid = threadIdx.x;

    __shared__ f2   s_all2[ALL_];
    __shared__ float s_pre[16];
    __shared__ float s_pim[16];
    __shared__ int   s_hist[32];
    __shared__ int   s_binStart[32];
    __shared__ int   s_binBase[32];

    float* s_f = (float*)s_all2;         // scalar view (component access)
    char*  sb  = (char*)s_all2;          // byte view (Phase B addressing)

    // build scratch aliases: f2 [N..N+2112) = 4224 ints (demap uses [0..N))
    int* sc        = (int*)(s_all2 + N_);
    int* s_deg     = sc;                 // [K] degree
    int* s_perm    = sc + K_;            // [K] slot -> v | deg<<16
    int* s_offslot = sc + 2 * K_;        // [K] v -> base | slot<<16
    int* s_cnt     = sc + 3 * K_;        // [K] edge-fill cursors

    if (tid < 16) {
        s_pre[tid] = points_re[tid];
        s_pim[tid] = points_im[tid];
    }
    if (tid < 32) s_hist[tid] = 0;

    const float eb    = ebno_db[0];
    const float no    = 1.0f / ((powf(10.0f, eb / 10.0f) * 0.5f) * 4.0f);
    const float sigma = sqrtf(no / 2.0f);

    // ---- stage info bits (0/1 floats, both codewords); out0 = bits ----
    for (int i = tid; i < K_; i += BS_) {
        int v0 = bits[b0 * K_ + i];
        int v1 = bits[b1 * K_ + i];
        s_f[2 * i + 0] = (float)v0;
        s_f[2 * i + 1] = (float)v1;
        out[b0 * K_ + i] = (float)v0;
        out[b1 * K_ + i] = (float)v1;
    }
    __syncthreads();

    // ---- parity: XOR of DV gathered info bits (both cw, pk adds) ----
    for (int m = tid; m < M_; m += BS_) {
        f2 acc = (f2)0.0f;
        #pragma unroll
        for (int d = 0; d < DV_; ++d) acc = acc + s_all2[a_idx[m * DV_ + d]];
        f2 p;
        p.x = (float)(((int)acc.x) & 1);
        p.y = (float)(((int)acc.y) & 1);
        s_all2[K_ + m] = p;
    }
    for (int v = tid; v < K_; v += BS_) { s_deg[v] = 0; s_cnt[v] = 0; }
    __syncthreads();

    // ---- QAM + AWGN + exact APP demap, per-(symbol,codeword) tasks ----
    // R28 one-eval form: max pass then sum pass, each evaluating every
    // point's lg ONCE; per-bit update order over p unchanged (ascending)
    // -> bit-identical to the old per-bit two-pass form.
    // ---- overlapped: VN degree count (disjoint LDS region)         ----
    for (int tsk = tid; tsk < NCW_ * NSYM_; tsk += BS_) {
        int cw = (tsk >= NSYM_) ? 1 : 0;
        int s  = tsk - cw * NSYM_;
        int bcw = b0 + cw;
        int c0 = (int)s_f[2 * (4 * s + 0) + cw];
        int c1 = (int)s_f[2 * (4 * s + 1) + cw];
        int c2 = (int)s_f[2 * (4 * s + 2) + cw];
        int c3 = (int)s_f[2 * (4 * s + 3) + cw];
        int sym = c0 * 8 + c1 * 4 + c2 * 2 + c3;
        float yre = s_pre[sym] + sigma * noise_re[bcw * NSYM_ + s];
        float yim = s_pim[sym] + sigma * noise_im[bcw * NSYM_ + s];
        float m0[4], m1[4];
        #pragma unroll
        for (int j = 0; j < 4; ++j) { m0[j] = -1e30f; m1[j] = -1e30f; }
        // pass 1: maxes, one lg eval per point (same fp expression)
        #pragma unroll
        for (int p = 0; p < 16; ++p) {
            float dre  = yre - s_pre[p];
            float dim_ = yim - s_pim[p];
            float lg   = -(dre * dre + dim_ * dim_) / no;
            #pragma unroll
            for (int j = 0; j < 4; ++j) {
                if (((p >> (3 - j)) & 1) == 0) m0[j] = fmaxf(m0[j], lg);
                else                           m1[j] = fmaxf(m1[j], lg);
            }
        }
        // pass 2: sums, one lg eval per point (identical fp sequence,
        // ascending p per bit)
        float s0[4], s1[4];
        #pragma unroll
        for (int j = 0; j < 4; ++j) { s0[j] = 0.0f; s1[j] = 0.0f; }
        #pragma unroll
        for (int p = 0; p < 16; ++p) {
            float dre  = yre - s_pre[p];
            float dim_ = yim - s_pim[p];
            float lg   = -(dre * dre + dim_ * dim_) / no;
            #pragma unroll
            for (int j = 0; j < 4; ++j) {
                if (((p >> (3 - j)) & 1) == 0) s0[j] += __expf(lg - m0[j]);
                else                           s1[j] += __expf(lg - m1[j]);
            }
        }
        #pragma unroll
        for (int j = 0; j < 4; ++j) {
            float llr = (m0[j] + __logf(s0[j])) - (m1[j] + __logf(s1[j]));
            s_f[2 * (4 * s + j) + cw] = llr * LOG2E_;
        }
    }
    for (int idx = tid; idx < NIE_; idx += BS_) {
        int m = idx / 5, j = idx - m * 5;
        atomicAdd(&s_deg[edge_vn[m * ROW_ + j]], 1);
    }
    __syncthreads();

    // ---- degree histogram -> arithmetic segment bases (scan-free) ----
    for (int v = tid; v < K_; v += BS_) atomicAdd(&s_hist[s_deg[v] & 31], 1);
    __syncthreads();
    if (tid == 0) {
        int accS = 0, accB = 0;
        for (int d = 0; d < 32; ++d) {
            int c = s_hist[d];
            s_binStart[d] = accS;
            s_binBase[d]  = accB;
            s_hist[d]     = accS;        // reuse as sort cursor
            accS += c;
            accB += c * seg_stride(d);   // odd stride -> conflict-free
        }
    }
    __syncthreads();
    for (int v = tid; v < K_; v += BS_) {   // counting sort by degree
        int d    = s_deg[v];
        int slot = atomicAdd(&s_hist[d & 31], 1);
        int base = s_binBase[d] + (slot - s_binStart[d]) * seg_stride(d);
        s_perm[slot]  = v | (d << 16);
        s_offslot[v]  = base | (slot << 16);
    }
    __syncthreads();

    // ---- capture iteration-invariant state in registers ----
    unsigned od[KMAX_];                  // base | deg<<13 | pv<<18
    f2       lr[KMAX_];                  // channel LLR_hat (both cw)
    #pragma unroll
    for (int k = 0; k < KMAX_; ++k) {
        int s = tid + BS_ * k;
        if (s < K_) {
            int w = s_perm[s];
            int v = w & 0xFFFF;
            int d = w >> 16;
            int base = s_binBase[d] + (s - s_binStart[d]) * seg_stride(d);
            od[k] = (unsigned)base | ((unsigned)d << 13) | ((unsigned)v << 18);
            lr[k] = s_all2[v];
            s_all2[CAP_ + s] = lr[k];    // iter-0 marginal == channel LLR
        } else { od[k] = 0; lr[k] = (f2)0.0f; }
    }
    f2       t5[KMAX_];
    unsigned vnp[KMAX_][5];              // slotByte | eposByte<<16 (x8 units)
    f2       c2v[KMAX_][5];              // c2v register file (both cw)
    #pragma unroll
    for (int kk = 0; kk < KMAX_; ++kk) {
        int m = tid + BS_ * kk;
        if (m < M_) {
            #pragma unroll
            for (int j = 0; j < 5; ++j) {
                int v = edge_vn[m * ROW_ + j];
                int r = atomicAdd(&s_cnt[v], 1);
                int w = s_offslot[v];
                int slot = w >> 16;
                int epos = (w & 0xFFFF) + r;
                vnp[kk][j] = (unsigned)(slot << 3) | ((unsigned)(epos << 3) << 16);
                c2v[kk][j] = (f2)0.0f;
            }
            f2 lrP = s_all2[K_ + m];
            float avx = __builtin_amdgcn_fmed3f(fabsf(lrP.x), AVLO_, AVHI_);
            float avy = __builtin_amdgcn_fmed3f(fabsf(lrP.y), AVLO_, AVHI_);
            f2 e2; e2.x = fexp2(-avx); e2.y = fexp2(-avy);
            f2 om = 1.0f - e2;           // pk
            f2 op = 1.0f + e2;           // pk
            f2 u2; u2.x = frcp(op.x); u2.y = frcp(op.y);
            f2 tm2 = om * u2;            // pk
            f2 t;
            t.x = copysignf(tm2.x, lrP.x);
            t.y = copysignf(tm2.y, lrP.y);
            t5[kk] = t;
        } else {
            t5[kk] = (f2)0.0f;
            #pragma unroll
            for (int j = 0; j < 5; ++j) {
                vnp[kk][j] = 0; c2v[kk][j] = (f2)0.0f;
            }
        }
    }
    __syncthreads();
    // staging + build scratch fully consumed -> zero edge-slot array
    for (int i = tid; i < CAP_; i += BS_) s_all2[i] = (f2)0.0f;
    __syncthreads();

    // ---- sum-product BP, flooding (bits domain), {B; A} x NITER ----
    for (int it = 0; it < NITER_; ++it) {
        // Phase B: CN update, both codewords per b64 LDS op; old c2v from
        // registers; pk mul/add pairs + scalar trans per component.
        #pragma unroll
        for (int kk = 0; kk < KMAX_; ++kk) {
            int m = tid + BS_ * kk;
            if (m < M_) {
                f2 tj[5];
                #pragma unroll
                for (int j = 0; j < 5; ++j) {
                    unsigned w = vnp[kk][j];
                    f2 mgv = *(const f2*)(sb +
                             ((w & 0xFFFFu) + (unsigned)(CAP_ * 8)));
                    f2 v2 = mgv - c2v[kk][j];          // pk sub
                    float avx = __builtin_amdgcn_fmed3f(fabsf(v2.x), AVLO_, AVHI_);
                    float avy = __builtin_amdgcn_fmed3f(fabsf(v2.y), AVLO_, AVHI_);
                    f2 e2; e2.x = fexp2(-avx); e2.y = fexp2(-avy);
                    f2 om = 1.0f - e2;                 // pk
                    f2 op = 1.0f + e2;                 // pk
                    f2 u2; u2.x = frcp(op.x); u2.y = frcp(op.y);
                    f2 tm2 = om * u2;                  // pk
                    f2 t;
                    t.x = copysignf(tm2.x, v2.x);
                    t.y = copysignf(tm2.y, v2.y);
                    tj[j] = t;
                }
                f2 q[5];
                f2 pr = t5[kk];
                #pragma unroll
                for (int j = 0; j < 5; ++j) {
                    q[j] = pr;
                    pr = pr * tj[j];                   // pk
                }
                f2 sf = (f2)1.0f;
                #pragma unroll
                for (int j = 4; j >= 0; --j) {
                    q[j] = q[j] * sf;                  // pk
                    sf = sf * tj[j];                   // pk
                }
                #pragma unroll
                for (int j = 0; j < 5; ++j) {
                    f2 qc;
                    qc.x = __builtin_amdgcn_fmed3f(q[j].x, -QC_, QC_);
                    qc.y = __builtin_amdgcn_fmed3f(q[j].y, -QC_, QC_);
                    f2 opq = 1.0f + qc;                // pk
                    f2 omq = 1.0f - qc;                // pk
                    f2 w2; w2.x = frcp(omq.x); w2.y = frcp(omq.y);
                    f2 ar = opq * w2;                  // pk
                    f2 r; r.x = flog2(ar.x); r.y = flog2(ar.y);
                    c2v[kk][j] = r;
                    *(f2*)(sb + (vnp[kk][j] >> 16)) = r;
                }
            }
        }
        __syncthreads();
        // Phase A: slot-indexed marginals; odd-stride sequential b64
        // segment reads, degree-switch unrolled (R28). Last iteration
        // doubles as the final marginal + hard decision.
        #pragma unroll
        for (int k = 0; k < KMAX_; ++k) {
            int s = tid + BS_ * k;
            if (s < K_) {
                int base = (int)(od[k] & 0x1FFFu);
                int dg   = (int)((od[k] >> 13) & 31u);
                f2 mg = seg_acc(s_all2 + base, dg, lr[k]);
                s_all2[CAP_ + s] = mg;
                if (it == NITER_ - 1) {
                    int pv = (int)(od[k] >> 18);
                    out[(size_t)BATCH_ * K_ + b0 * K_ + pv] = (mg.x < 0.0f) ? 1.0f : 0.0f;
                    out[(size_t)BATCH_ * K_ + b1 * K_ + pv] = (mg.y < 0.0f) ? 1.0f : 0.0f;
                }
            }
        }
        __syncthreads();
    }
}

extern "C" void kernel_launch(void* const* d_in, const int* in_sizes, int n_in,
                              void* d_out, int out_size, void* d_ws, size_t ws_size,
                              hipStream_t stream) {
    const int*   bits    = (const int*)  d_in[0];
    const int*   a_idx   = (const int*)  d_in[1];
    // d_in[2] = edge_cn (implicit: contiguous groups of 6) — unused
    const int*   edge_vn = (const int*)  d_in[3];
    const float* pre     = (const float*)d_in[4];
    const float* pim     = (const float*)d_in[5];
    const float* nre     = (const float*)d_in[6];
    const float* nim     = (const float*)d_in[7];
    const float* ebno    = (const float*)d_in[8];

    link_kernel<<<BATCH_ / NCW_, BS_, 0, stream>>>(bits, a_idx, pre, pim, nre, nim,
                                                   ebno, edge_vn, (float*)d_out);
}

// Round 10
// 173.105 us; speedup vs baseline: 1.0416x; 1.0416x over previous
//
#include <hip/hip_runtime.h>

// Problem constants (match reference)
#define K_     1056
#define N_     2112
#define M_     1056   // N - K
#define E_     6336   // M * 6
#define NIE_   5280   // M * 5 info-side edges (the only BP state)
#define CAP_   6336   // padded c2v extent upper bound (stride = d|1 adds <=1/VN)
#define ALL_   7392   // CAP_ + K_ : c2v + marg unified array (float2 units)
#define DV_    5
#define ROW_   6      // edge 6m+5 is the parity VN K+m
#define NSYM_  528
#define NITER_ 20
#define BATCH_ 1024
#define BS_    1024   // 16 waves/block, 2 blocks/CU = 32 waves
#define KMAX_  2      // ceil(K_/BS_) work trips per thread
#define NCW_   2      // codewords per block (float2-packed payload)

#define LOG2E_ 1.4426950408889634f
#define AVLO_  (1e-6f * LOG2E_)          // |v2c| floor, bits units
#define AVHI_  (20.0f * LOG2E_)          // |v2c| cap,  bits units
#define QC_    0.99999988f               // tanh-domain cap (unchanged)

// ext_vector pair type -> backend emits v_pk_add_f32/v_pk_mul_f32
// (two independent IEEE fp32 lanes per instruction; per-component
// rounding identical to scalar -> bit-exact vs scalar form). [R27]
typedef float f2 __attribute__((ext_vector_type(2)));

// stride(d) = d | 1 : always ODD -> coprime with the 16 bank-pairs of a
// b64 access -> Phase A's wave-uniform-stride segment reads stay
// conflict-free in the float2 layout.
__device__ __forceinline__ int seg_stride(int d) { return d | 1; }

// Bare-instruction transcendentals (R17 win: OCML wrappers inflated the
// hot loop ~2x; inputs always normal-range, <=1 ULP deviation validated
// absmax-0 since R1).
__device__ __forceinline__ float fexp2(float x) { return __builtin_amdgcn_exp2f(x); }
__device__ __forceinline__ float flog2(float x) { return __builtin_amdgcn_logf(x); }
__device__ __forceinline__ float frcp(float x)  { return __builtin_amdgcn_rcpf(x); }

// -------------------------------------------------------------------------
// Single kernel, TWO codewords per block, 1024 threads / 16 waves.
// == R29: R27 BP loop (verbatim) + R28 one-eval demap ==
//
// R28 post-mortem: seg_acc degree-switch REGRESSED the BP loop
// (108.8 -> 117.8 us): 13 cases x ~12 ds_read each bloated Phase A
// ~10x, bin-straddling waves ran multiple cases serially, and branch/
// I-fetch stalls showed as LOWER VALUBusy (57) with HIGHER time.
// Second instance of "code-size specialization loses to tight generic
// loops" (after R18 CSR-gather). Phase A reverted to R27's d+=2 loop.
// The R28 demap rewrite is kept: one lg eval per point (2 passes)
// instead of 8 (4 bits x 2 passes), divisions 128->32 per task --
// pure recomputation elision, per-bit ascending-p order preserved ->
// bit-identical LLRs. Prologue-scale win, matches R28's WRITE drop.
//
// R25/R27 spill (~45-57MB WRITE) confirmed one-shot prologue,
// latency-hidden; all de-spill attempts (R21/22/24/26) lost to it.
//
// LDS map (f2 units, s_all2[7392] = 59136 B):
//   [0..CAP)   build: [0..N) staging (VN i -> {llr_cw0, llr_cw1}),
//              [N..N+2112) = 4224 ints of build scratch;
//              BP: c2v odd-stride VN-major segments (r-values)
//   [CAP..ALL) slot-indexed marginals (f2)
//
// Structure: H = [A | I]; parity VN deg-1 -> per-check constant t5;
// degree-sorted slots (wave-uniform Phase A trips); scan-free bases from
// 32-bin histogram; od packs base|deg<<13|pv<<18; atomic build order
// only permutes accumulation order (validated order-independent R4-R28).
//
// CN math per component (prefix/suffix partial products, bits domain):
//   t = copysign((1-2^-av)/(1+2^-av), v2c);  q_j = t5 * prod_{i!=j} t_i
//   q = med3(q, -QC, QC);  r = log2((1+q)/(1-q))
// -------------------------------------------------------------------------
__global__ __launch_bounds__(BS_, 8) void link_kernel(
    const int*   __restrict__ bits,      // [B,K]
    const int*   __restrict__ a_idx,     // [M,DV]
    const float* __restrict__ points_re, // [16]
    const float* __restrict__ points_im, // [16]
    const float* __restrict__ noise_re,  // [B,NSYM]
    const float* __restrict__ noise_im,  // [B,NSYM]
    const float* __restrict__ ebno_db,   // [1]
    const int*   __restrict__ edge_vn,   // [E]
    float*       __restrict__ out)       // [2,B,K]
{
#pragma clang fp contract(off)
    const int blk = blockIdx.x;
    const int b0  = blk * NCW_;          // codeword 0 (component .x)
    const int b1  = b0 + 1;              // codeword 1 (component .y)
    const int tid = threadIdx.x;

    __shared__ f2   s_all2[ALL_];
    __shared__ float s_pre[16];
    __shared__ float s_pim[16];
    __shared__ int   s_hist[32];
    __shared__ int   s_binStart[32];
    __shared__ int   s_binBase[32];

    float* s_f = (float*)s_all2;         // scalar view (component access)
    char*  sb  = (char*)s_all2;          // byte view (Phase B addressing)

    // build scratch aliases: f2 [N..N+2112) = 4224 ints (demap uses [0..N))
    int* sc        = (int*)(s_all2 + N_);
    int* s_deg     = sc;                 // [K] degree
    int* s_perm    = sc + K_;            // [K] slot -> v | deg<<16
    int* s_offslot = sc + 2 * K_;        // [K] v -> base | slot<<16
    int* s_cnt     = sc + 3 * K_;        // [K] edge-fill cursors

    if (tid < 16) {
        s_pre[tid] = points_re[tid];
        s_pim[tid] = points_im[tid];
    }
    if (tid < 32) s_hist[tid] = 0;

    const float eb    = ebno_db[0];
    const float no    = 1.0f / ((powf(10.0f, eb / 10.0f) * 0.5f) * 4.0f);
    const float sigma = sqrtf(no / 2.0f);

    // ---- stage info bits (0/1 floats, both codewords); out0 = bits ----
    for (int i = tid; i < K_; i += BS_) {
        int v0 = bits[b0 * K_ + i];
        int v1 = bits[b1 * K_ + i];
        s_f[2 * i + 0] = (float)v0;
        s_f[2 * i + 1] = (float)v1;
        out[b0 * K_ + i] = (float)v0;
        out[b1 * K_ + i] = (float)v1;
    }
    __syncthreads();

    // ---- parity: XOR of DV gathered info bits (both cw, pk adds) ----
    for (int m = tid; m < M_; m += BS_) {
        f2 acc = (f2)0.0f;
        #pragma unroll
        for (int d = 0; d < DV_; ++d) acc = acc + s_all2[a_idx[m * DV_ + d]];
        f2 p;
        p.x = (float)(((int)acc.x) & 1);
        p.y = (float)(((int)acc.y) & 1);
        s_all2[K_ + m] = p;
    }
    for (int v = tid; v < K_; v += BS_) { s_deg[v] = 0; s_cnt[v] = 0; }
    __syncthreads();

    // ---- QAM + AWGN + exact APP demap, per-(symbol,codeword) tasks ----
    // R28 one-eval form: max pass then sum pass, each evaluating every
    // point's lg ONCE; per-bit update order over p unchanged (ascending)
    // -> bit-identical to the per-bit two-pass form.
    // ---- overlapped: VN degree count (disjoint LDS region)         ----
    for (int tsk = tid; tsk < NCW_ * NSYM_; tsk += BS_) {
        int cw = (tsk >= NSYM_) ? 1 : 0;
        int s  = tsk - cw * NSYM_;
        int bcw = b0 + cw;
        int c0 = (int)s_f[2 * (4 * s + 0) + cw];
        int c1 = (int)s_f[2 * (4 * s + 1) + cw];
        int c2 = (int)s_f[2 * (4 * s + 2) + cw];
        int c3 = (int)s_f[2 * (4 * s + 3) + cw];
        int sym = c0 * 8 + c1 * 4 + c2 * 2 + c3;
        float yre = s_pre[sym] + sigma * noise_re[bcw * NSYM_ + s];
        float yim = s_pim[sym] + sigma * noise_im[bcw * NSYM_ + s];
        float m0[4], m1[4];
        #pragma unroll
        for (int j = 0; j < 4; ++j) { m0[j] = -1e30f; m1[j] = -1e30f; }
        // pass 1: maxes, one lg eval per point (same fp expression)
        #pragma unroll
        for (int p = 0; p < 16; ++p) {
            float dre  = yre - s_pre[p];
            float dim_ = yim - s_pim[p];
            float lg   = -(dre * dre + dim_ * dim_) / no;
            #pragma unroll
            for (int j = 0; j < 4; ++j) {
                if (((p >> (3 - j)) & 1) == 0) m0[j] = fmaxf(m0[j], lg);
                else                           m1[j] = fmaxf(m1[j], lg);
            }
        }
        // pass 2: sums, one lg eval per point (identical fp sequence,
        // ascending p per bit)
        float s0[4], s1[4];
        #pragma unroll
        for (int j = 0; j < 4; ++j) { s0[j] = 0.0f; s1[j] = 0.0f; }
        #pragma unroll
        for (int p = 0; p < 16; ++p) {
            float dre  = yre - s_pre[p];
            float dim_ = yim - s_pim[p];
            float lg   = -(dre * dre + dim_ * dim_) / no;
            #pragma unroll
            for (int j = 0; j < 4; ++j) {
                if (((p >> (3 - j)) & 1) == 0) s0[j] += __expf(lg - m0[j]);
                else                           s1[j] += __expf(lg - m1[j]);
            }
        }
        #pragma unroll
        for (int j = 0; j < 4; ++j) {
            float llr = (m0[j] + __logf(s0[j])) - (m1[j] + __logf(s1[j]));
            s_f[2 * (4 * s + j) + cw] = llr * LOG2E_;
        }
    }
    for (int idx = tid; idx < NIE_; idx += BS_) {
        int m = idx / 5, j = idx - m * 5;
        atomicAdd(&s_deg[edge_vn[m * ROW_ + j]], 1);
    }
    __syncthreads();

    // ---- degree histogram -> arithmetic segment bases (scan-free) ----
    for (int v = tid; v < K_; v += BS_) atomicAdd(&s_hist[s_deg[v] & 31], 1);
    __syncthreads();
    if (tid == 0) {
        int accS = 0, accB = 0;
        for (int d = 0; d < 32; ++d) {
            int c = s_hist[d];
            s_binStart[d] = accS;
            s_binBase[d]  = accB;
            s_hist[d]     = accS;        // reuse as sort cursor
            accS += c;
            accB += c * seg_stride(d);   // odd stride -> conflict-free
        }
    }
    __syncthreads();
    for (int v = tid; v < K_; v += BS_) {   // counting sort by degree
        int d    = s_deg[v];
        int slot = atomicAdd(&s_hist[d & 31], 1);
        int base = s_binBase[d] + (slot - s_binStart[d]) * seg_stride(d);
        s_perm[slot]  = v | (d << 16);
        s_offslot[v]  = base | (slot << 16);
    }
    __syncthreads();

    // ---- capture iteration-invariant state in registers ----
    unsigned od[KMAX_];                  // base | deg<<13 | pv<<18
    f2       lr[KMAX_];                  // channel LLR_hat (both cw)
    #pragma unroll
    for (int k = 0; k < KMAX_; ++k) {
        int s = tid + BS_ * k;
        if (s < K_) {
            int w = s_perm[s];
            int v = w & 0xFFFF;
            int d = w >> 16;
            int base = s_binBase[d] + (s - s_binStart[d]) * seg_stride(d);
            od[k] = (unsigned)base | ((unsigned)d << 13) | ((unsigned)v << 18);
            lr[k] = s_all2[v];
            s_all2[CAP_ + s] = lr[k];    // iter-0 marginal == channel LLR
        } else { od[k] = 0; lr[k] = (f2)0.0f; }
    }
    f2       t5[KMAX_];
    unsigned vnp[KMAX_][5];              // slotByte | eposByte<<16 (x8 units)
    f2       c2v[KMAX_][5];              // c2v register file (both cw)
    #pragma unroll
    for (int kk = 0; kk < KMAX_; ++kk) {
        int m = tid + BS_ * kk;
        if (m < M_) {
            #pragma unroll
            for (int j = 0; j < 5; ++j) {
                int v = edge_vn[m * ROW_ + j];
                int r = atomicAdd(&s_cnt[v], 1);
                int w = s_offslot[v];
                int slot = w >> 16;
                int epos = (w & 0xFFFF) + r;
                vnp[kk][j] = (unsigned)(slot << 3) | ((unsigned)(epos << 3) << 16);
                c2v[kk][j] = (f2)0.0f;
            }
            f2 lrP = s_all2[K_ + m];
            float avx = __builtin_amdgcn_fmed3f(fabsf(lrP.x), AVLO_, AVHI_);
            float avy = __builtin_amdgcn_fmed3f(fabsf(lrP.y), AVLO_, AVHI_);
            f2 e2; e2.x = fexp2(-avx); e2.y = fexp2(-avy);
            f2 om = 1.0f - e2;           // pk
            f2 op = 1.0f + e2;           // pk
            f2 u2; u2.x = frcp(op.x); u2.y = frcp(op.y);
            f2 tm2 = om * u2;            // pk
            f2 t;
            t.x = copysignf(tm2.x, lrP.x);
            t.y = copysignf(tm2.y, lrP.y);
            t5[kk] = t;
        } else {
            t5[kk] = (f2)0.0f;
            #pragma unroll
            for (int j = 0; j < 5; ++j) {
                vnp[kk][j] = 0; c2v[kk][j] = (f2)0.0f;
            }
        }
    }
    __syncthreads();
    // staging + build scratch fully consumed -> zero edge-slot array
    for (int i = tid; i < CAP_; i += BS_) s_all2[i] = (f2)0.0f;
    __syncthreads();

    // ---- sum-product BP, flooding (bits domain), {B; A} x NITER ----
    for (int it = 0; it < NITER_; ++it) {
        // Phase B: CN update, both codewords per b64 LDS op; old c2v from
        // registers; pk mul/add pairs + scalar trans per component.
        #pragma unroll
        for (int kk = 0; kk < KMAX_; ++kk) {
            int m = tid + BS_ * kk;
            if (m < M_) {
                f2 tj[5];
                #pragma unroll
                for (int j = 0; j < 5; ++j) {
                    unsigned w = vnp[kk][j];
                    f2 mgv = *(const f2*)(sb +
                             ((w & 0xFFFFu) + (unsigned)(CAP_ * 8)));
                    f2 v2 = mgv - c2v[kk][j];          // pk sub
                    float avx = __builtin_amdgcn_fmed3f(fabsf(v2.x), AVLO_, AVHI_);
                    float avy = __builtin_amdgcn_fmed3f(fabsf(v2.y), AVLO_, AVHI_);
                    f2 e2; e2.x = fexp2(-avx); e2.y = fexp2(-avy);
                    f2 om = 1.0f - e2;                 // pk
                    f2 op = 1.0f + e2;                 // pk
                    f2 u2; u2.x = frcp(op.x); u2.y = frcp(op.y);
                    f2 tm2 = om * u2;                  // pk
                    f2 t;
                    t.x = copysignf(tm2.x, v2.x);
                    t.y = copysignf(tm2.y, v2.y);
                    tj[j] = t;
                }
                f2 q[5];
                f2 pr = t5[kk];
                #pragma unroll
                for (int j = 0; j < 5; ++j) {
                    q[j] = pr;
                    pr = pr * tj[j];                   // pk
                }
                f2 sf = (f2)1.0f;
                #pragma unroll
                for (int j = 4; j >= 0; --j) {
                    q[j] = q[j] * sf;                  // pk
                    sf = sf * tj[j];                   // pk
                }
                #pragma unroll
                for (int j = 0; j < 5; ++j) {
                    f2 qc;
                    qc.x = __builtin_amdgcn_fmed3f(q[j].x, -QC_, QC_);
                    qc.y = __builtin_amdgcn_fmed3f(q[j].y, -QC_, QC_);
                    f2 opq = 1.0f + qc;                // pk
                    f2 omq = 1.0f - qc;                // pk
                    f2 w2; w2.x = frcp(omq.x); w2.y = frcp(omq.y);
                    f2 ar = opq * w2;                  // pk
                    f2 r; r.x = flog2(ar.x); r.y = flog2(ar.y);
                    c2v[kk][j] = r;
                    *(f2*)(sb + (vnp[kk][j] >> 16)) = r;
                }
            }
        }
        __syncthreads();
        // Phase A: slot-indexed marginals; odd-stride sequential b64
        // segment reads, pk adds (R27 generic loop — R28's degree-switch
        // regressed). Last iteration doubles as the final marginal +
        // hard decision.
        #pragma unroll
        for (int k = 0; k < KMAX_; ++k) {
            int s = tid + BS_ * k;
            if (s < K_) {
                int base = (int)(od[k] & 0x1FFFu);
                int dg   = (int)((od[k] >> 13) & 31u);
                f2 mg = lr[k];
                int d = 0;
                for (; d + 1 < dg; d += 2) {
                    mg = mg + s_all2[base + d];        // pk
                    mg = mg + s_all2[base + d + 1];    // pk
                }
                if (d < dg) mg = mg + s_all2[base + d];// pk
                s_all2[CAP_ + s] = mg;
                if (it == NITER_ - 1) {
                    int pv = (int)(od[k] >> 18);
                    out[(size_t)BATCH_ * K_ + b0 * K_ + pv] = (mg.x < 0.0f) ? 1.0f : 0.0f;
                    out[(size_t)BATCH_ * K_ + b1 * K_ + pv] = (mg.y < 0.0f) ? 1.0f : 0.0f;
                }
            }
        }
        __syncthreads();
    }
}

extern "C" void kernel_launch(void* const* d_in, const int* in_sizes, int n_in,
                              void* d_out, int out_size, void* d_ws, size_t ws_size,
                              hipStream_t stream) {
    const int*   bits    = (const int*)  d_in[0];
    const int*   a_idx   = (const int*)  d_in[1];
    // d_in[2] = edge_cn (implicit: contiguous groups of 6) — unused
    const int*   edge_vn = (const int*)  d_in[3];
    const float* pre     = (const float*)d_in[4];
    const float* pim     = (const float*)d_in[5];
    const float* nre     = (const float*)d_in[6];
    const float* nim     = (const float*)d_in[7];
    const float* ebno    = (const float*)d_in[8];

    link_kernel<<<BATCH_ / NCW_, BS_, 0, stream>>>(bits, a_idx, pre, pim, nre, nim,
                                                   ebno, edge_vn, (float*)d_out);
}

// Round 11
// 172.987 us; speedup vs baseline: 1.0423x; 1.0007x over previous
//
#include <hip/hip_runtime.h>

// Problem constants (match reference)
#define K_     1056
#define N_     2112
#define M_     1056   // N - K
#define E_     6336   // M * 6
#define NIE_   5280   // M * 5 info-side edges (the only BP state)
#define CAP_   6336   // padded c2v extent upper bound (stride = d|1 adds <=1/VN)
#define ALL_   7392   // CAP_ + K_ : c2v + marg unified array (float2 units)
#define DV_    5
#define ROW_   6      // edge 6m+5 is the parity VN K+m
#define NSYM_  528
#define NITER_ 20
#define BATCH_ 1024
#define BS_    1024   // 16 waves/block, 2 blocks/CU = 32 waves
#define KMAX_  2      // ceil(K_/BS_) work trips per thread
#define NCW_   2      // codewords per block (float2-packed payload)

#define LOG2E_ 1.4426950408889634f
#define AVLO_  (1e-6f * LOG2E_)          // |v2c| floor, bits units
#define AVHI_  (20.0f * LOG2E_)          // |v2c| cap,  bits units
#define QC_    0.99999988f               // tanh-domain cap (unchanged)

// ext_vector pair type -> backend emits v_pk_add_f32/v_pk_mul_f32
// (two independent IEEE fp32 lanes per instruction; per-component
// rounding identical to scalar -> bit-exact vs scalar form). [R27]
typedef float f2 __attribute__((ext_vector_type(2)));

// stride(d) = d | 1 : always ODD -> coprime with the 16 bank-pairs of a
// b64 access -> Phase A's wave-uniform-stride segment reads stay
// conflict-free in the float2 layout.
__device__ __forceinline__ int seg_stride(int d) { return d | 1; }

// Bare-instruction transcendentals (R17 win: OCML wrappers inflated the
// hot loop ~2x; inputs always normal-range, <=1 ULP deviation validated
// absmax-0 since R1).
__device__ __forceinline__ float fexp2(float x) { return __builtin_amdgcn_exp2f(x); }
__device__ __forceinline__ float flog2(float x) { return __builtin_amdgcn_logf(x); }
__device__ __forceinline__ float frcp(float x)  { return __builtin_amdgcn_rcpf(x); }

// -------------------------------------------------------------------------
// Single kernel, TWO codewords per block, 1024 threads / 16 waves.
// == R30: restore R27 verbatim (measured champion, 108.8 us) ==
//
// Final ledger of the structural axes (all counter-bracketed):
//  - occupancy: 32 waves/CU optimal; every de-spill trade (R21/22/24/26)
//    lost waves and lost time; the ~57MB WRITE is one-shot prologue
//    spill, latency-hidden.
//  - LDS: dual-codeword f2 payload halves ops (R25, -4.1us); conflicts
//    1.34e7 = ~8 extra cy per random wave-op, bounded by graph
//    randomness; odd-stride segments keep Phase A conflict-free.
//  - VALU: v_pk packing of all pairwise mul/add/sub (R27, -3.7us).
//  - Phase A generic d+=2 loop beats degree-switch (R28: -9us regress)
//    and CSR-gather (R18) -- tight generic loops win here.
//  - demap one-eval (R28/R29): no wall-clock effect; prologue is hidden
//    behind BP startup -> reverted to R19 per-bit streaming form.
//  - per-edge math frozen (absmax-0 discipline): 4 trans + ~10 VALU per
//    edge-pair; algebraic alternatives trade trans for more VALU.
// Budget at 109us: trans issue ~44us, LDS BW+conflicts ~45us, other
// VALU ~35us, partially overlapped. No >20% removable share remains
// without changing the math sequence.
//
// LDS map (f2 units, s_all2[7392] = 59136 B):
//   [0..CAP)   build: [0..N) staging (VN i -> {llr_cw0, llr_cw1}),
//              [N..N+2112) = 4224 ints of build scratch;
//              BP: c2v odd-stride VN-major segments (r-values)
//   [CAP..ALL) slot-indexed marginals (f2)
//
// Structure: H = [A | I]; parity VN deg-1 -> per-check constant t5;
// degree-sorted slots (wave-uniform Phase A trips); scan-free bases from
// 32-bin histogram; od packs base|deg<<13|pv<<18; atomic build order
// only permutes accumulation order (validated order-independent R4-R29).
//
// CN math per component (prefix/suffix partial products, bits domain):
//   t = copysign((1-2^-av)/(1+2^-av), v2c);  q_j = t5 * prod_{i!=j} t_i
//   q = med3(q, -QC, QC);  r = log2((1+q)/(1-q))
// -------------------------------------------------------------------------
__global__ __launch_bounds__(BS_, 8) void link_kernel(
    const int*   __restrict__ bits,      // [B,K]
    const int*   __restrict__ a_idx,     // [M,DV]
    const float* __restrict__ points_re, // [16]
    const float* __restrict__ points_im, // [16]
    const float* __restrict__ noise_re,  // [B,NSYM]
    const float* __restrict__ noise_im,  // [B,NSYM]
    const float* __restrict__ ebno_db,   // [1]
    const int*   __restrict__ edge_vn,   // [E]
    float*       __restrict__ out)       // [2,B,K]
{
#pragma clang fp contract(off)
    const int blk = blockIdx.x;
    const int b0  = blk * NCW_;          // codeword 0 (component .x)
    const int b1  = b0 + 1;              // codeword 1 (component .y)
    const int tid = threadIdx.x;

    __shared__ f2   s_all2[ALL_];
    __shared__ float s_pre[16];
    __shared__ float s_pim[16];
    __shared__ int   s_hist[32];
    __shared__ int   s_binStart[32];
    __shared__ int   s_binBase[32];

    float* s_f = (float*)s_all2;         // scalar view (component access)
    char*  sb  = (char*)s_all2;          // byte view (Phase B addressing)

    // build scratch aliases: f2 [N..N+2112) = 4224 ints (demap uses [0..N))
    int* sc        = (int*)(s_all2 + N_);
    int* s_deg     = sc;                 // [K] degree
    int* s_perm    = sc + K_;            // [K] slot -> v | deg<<16
    int* s_offslot = sc + 2 * K_;        // [K] v -> base | slot<<16
    int* s_cnt     = sc + 3 * K_;        // [K] edge-fill cursors

    if (tid < 16) {
        s_pre[tid] = points_re[tid];
        s_pim[tid] = points_im[tid];
    }
    if (tid < 32) s_hist[tid] = 0;

    const float eb    = ebno_db[0];
    const float no    = 1.0f / ((powf(10.0f, eb / 10.0f) * 0.5f) * 4.0f);
    const float sigma = sqrtf(no / 2.0f);

    // ---- stage info bits (0/1 floats, both codewords); out0 = bits ----
    for (int i = tid; i < K_; i += BS_) {
        int v0 = bits[b0 * K_ + i];
        int v1 = bits[b1 * K_ + i];
        s_f[2 * i + 0] = (float)v0;
        s_f[2 * i + 1] = (float)v1;
        out[b0 * K_ + i] = (float)v0;
        out[b1 * K_ + i] = (float)v1;
    }
    __syncthreads();

    // ---- parity: XOR of DV gathered info bits (both cw, pk adds) ----
    for (int m = tid; m < M_; m += BS_) {
        f2 acc = (f2)0.0f;
        #pragma unroll
        for (int d = 0; d < DV_; ++d) acc = acc + s_all2[a_idx[m * DV_ + d]];
        f2 p;
        p.x = (float)(((int)acc.x) & 1);
        p.y = (float)(((int)acc.y) & 1);
        s_all2[K_ + m] = p;
    }
    for (int v = tid; v < K_; v += BS_) { s_deg[v] = 0; s_cnt[v] = 0; }
    __syncthreads();

    // ---- QAM + AWGN + exact APP demap, per-(symbol,codeword) tasks ----
    // R19 per-bit streaming form (2-reg max pass + 2-reg sum pass per
    // bit): caps live registers; prologue is latency-hidden anyway
    // (R29 lesson: demap VALU cuts don't reach wall clock).
    // ---- overlapped: VN degree count (disjoint LDS region)         ----
    for (int tsk = tid; tsk < NCW_ * NSYM_; tsk += BS_) {
        int cw = (tsk >= NSYM_) ? 1 : 0;
        int s  = tsk - cw * NSYM_;
        int bcw = b0 + cw;
        int c0 = (int)s_f[2 * (4 * s + 0) + cw];
        int c1 = (int)s_f[2 * (4 * s + 1) + cw];
        int c2 = (int)s_f[2 * (4 * s + 2) + cw];
        int c3 = (int)s_f[2 * (4 * s + 3) + cw];
        int sym = c0 * 8 + c1 * 4 + c2 * 2 + c3;
        float yre = s_pre[sym] + sigma * noise_re[bcw * NSYM_ + s];
        float yim = s_pim[sym] + sigma * noise_im[bcw * NSYM_ + s];
        #pragma unroll
        for (int j = 0; j < 4; ++j) {
            // pass 1: maxes for bit j (ascending p, same comparisons)
            float m0 = -1e30f, m1 = -1e30f;
            #pragma unroll
            for (int p = 0; p < 16; ++p) {
                float dre  = yre - s_pre[p];
                float dim_ = yim - s_pim[p];
                float lg   = -(dre * dre + dim_ * dim_) / no;
                if (((p >> (3 - j)) & 1) == 0) m0 = fmaxf(m0, lg);
                else                           m1 = fmaxf(m1, lg);
            }
            // pass 2: sums for bit j (identical fp sequence, ascending p)
            float sum0 = 0.0f, sum1 = 0.0f;
            #pragma unroll
            for (int p = 0; p < 16; ++p) {
                float dre  = yre - s_pre[p];
                float dim_ = yim - s_pim[p];
                float lg   = -(dre * dre + dim_ * dim_) / no;
                if (((p >> (3 - j)) & 1) == 0) sum0 += __expf(lg - m0);
                else                           sum1 += __expf(lg - m1);
            }
            float llr = (m0 + __logf(sum0)) - (m1 + __logf(sum1));
            s_f[2 * (4 * s + j) + cw] = llr * LOG2E_;
        }
    }
    for (int idx = tid; idx < NIE_; idx += BS_) {
        int m = idx / 5, j = idx - m * 5;
        atomicAdd(&s_deg[edge_vn[m * ROW_ + j]], 1);
    }
    __syncthreads();

    // ---- degree histogram -> arithmetic segment bases (scan-free) ----
    for (int v = tid; v < K_; v += BS_) atomicAdd(&s_hist[s_deg[v] & 31], 1);
    __syncthreads();
    if (tid == 0) {
        int accS = 0, accB = 0;
        for (int d = 0; d < 32; ++d) {
            int c = s_hist[d];
            s_binStart[d] = accS;
            s_binBase[d]  = accB;
            s_hist[d]     = accS;        // reuse as sort cursor
            accS += c;
            accB += c * seg_stride(d);   // odd stride -> conflict-free
        }
    }
    __syncthreads();
    for (int v = tid; v < K_; v += BS_) {   // counting sort by degree
        int d    = s_deg[v];
        int slot = atomicAdd(&s_hist[d & 31], 1);
        int base = s_binBase[d] + (slot - s_binStart[d]) * seg_stride(d);
        s_perm[slot]  = v | (d << 16);
        s_offslot[v]  = base | (slot << 16);
    }
    __syncthreads();

    // ---- capture iteration-invariant state in registers ----
    unsigned od[KMAX_];                  // base | deg<<13 | pv<<18
    f2       lr[KMAX_];                  // channel LLR_hat (both cw)
    #pragma unroll
    for (int k = 0; k < KMAX_; ++k) {
        int s = tid + BS_ * k;
        if (s < K_) {
            int w = s_perm[s];
            int v = w & 0xFFFF;
            int d = w >> 16;
            int base = s_binBase[d] + (s - s_binStart[d]) * seg_stride(d);
            od[k] = (unsigned)base | ((unsigned)d << 13) | ((unsigned)v << 18);
            lr[k] = s_all2[v];
            s_all2[CAP_ + s] = lr[k];    // iter-0 marginal == channel LLR
        } else { od[k] = 0; lr[k] = (f2)0.0f; }
    }
    f2       t5[KMAX_];
    unsigned vnp[KMAX_][5];              // slotByte | eposByte<<16 (x8 units)
    f2       c2v[KMAX_][5];              // c2v register file (both cw)
    #pragma unroll
    for (int kk = 0; kk < KMAX_; ++kk) {
        int m = tid + BS_ * kk;
        if (m < M_) {
            #pragma unroll
            for (int j = 0; j < 5; ++j) {
                int v = edge_vn[m * ROW_ + j];
                int r = atomicAdd(&s_cnt[v], 1);
                int w = s_offslot[v];
                int slot = w >> 16;
                int epos = (w & 0xFFFF) + r;
                vnp[kk][j] = (unsigned)(slot << 3) | ((unsigned)(epos << 3) << 16);
                c2v[kk][j] = (f2)0.0f;
            }
            f2 lrP = s_all2[K_ + m];
            float avx = __builtin_amdgcn_fmed3f(fabsf(lrP.x), AVLO_, AVHI_);
            float avy = __builtin_amdgcn_fmed3f(fabsf(lrP.y), AVLO_, AVHI_);
            f2 e2; e2.x = fexp2(-avx); e2.y = fexp2(-avy);
            f2 om = 1.0f - e2;           // pk
            f2 op = 1.0f + e2;           // pk
            f2 u2; u2.x = frcp(op.x); u2.y = frcp(op.y);
            f2 tm2 = om * u2;            // pk
            f2 t;
            t.x = copysignf(tm2.x, lrP.x);
            t.y = copysignf(tm2.y, lrP.y);
            t5[kk] = t;
        } else {
            t5[kk] = (f2)0.0f;
            #pragma unroll
            for (int j = 0; j < 5; ++j) {
                vnp[kk][j] = 0; c2v[kk][j] = (f2)0.0f;
            }
        }
    }
    __syncthreads();
    // staging + build scratch fully consumed -> zero edge-slot array
    for (int i = tid; i < CAP_; i += BS_) s_all2[i] = (f2)0.0f;
    __syncthreads();

    // ---- sum-product BP, flooding (bits domain), {B; A} x NITER ----
    for (int it = 0; it < NITER_; ++it) {
        // Phase B: CN update, both codewords per b64 LDS op; old c2v from
        // registers; pk mul/add pairs + scalar trans per component.
        #pragma unroll
        for (int kk = 0; kk < KMAX_; ++kk) {
            int m = tid + BS_ * kk;
            if (m < M_) {
                f2 tj[5];
                #pragma unroll
                for (int j = 0; j < 5; ++j) {
                    unsigned w = vnp[kk][j];
                    f2 mgv = *(const f2*)(sb +
                             ((w & 0xFFFFu) + (unsigned)(CAP_ * 8)));
                    f2 v2 = mgv - c2v[kk][j];          // pk sub
                    float avx = __builtin_amdgcn_fmed3f(fabsf(v2.x), AVLO_, AVHI_);
                    float avy = __builtin_amdgcn_fmed3f(fabsf(v2.y), AVLO_, AVHI_);
                    f2 e2; e2.x = fexp2(-avx); e2.y = fexp2(-avy);
                    f2 om = 1.0f - e2;                 // pk
                    f2 op = 1.0f + e2;                 // pk
                    f2 u2; u2.x = frcp(op.x); u2.y = frcp(op.y);
                    f2 tm2 = om * u2;                  // pk
                    f2 t;
                    t.x = copysignf(tm2.x, v2.x);
                    t.y = copysignf(tm2.y, v2.y);
                    tj[j] = t;
                }
                f2 q[5];
                f2 pr = t5[kk];
                #pragma unroll
                for (int j = 0; j < 5; ++j) {
                    q[j] = pr;
                    pr = pr * tj[j];                   // pk
                }
                f2 sf = (f2)1.0f;
                #pragma unroll
                for (int j = 4; j >= 0; --j) {
                    q[j] = q[j] * sf;                  // pk
                    sf = sf * tj[j];                   // pk
                }
                #pragma unroll
                for (int j = 0; j < 5; ++j) {
                    f2 qc;
                    qc.x = __builtin_amdgcn_fmed3f(q[j].x, -QC_, QC_);
                    qc.y = __builtin_amdgcn_fmed3f(q[j].y, -QC_, QC_);
                    f2 opq = 1.0f + qc;                // pk
                    f2 omq = 1.0f - qc;                // pk
                    f2 w2; w2.x = frcp(omq.x); w2.y = frcp(omq.y);
                    f2 ar = opq * w2;                  // pk
                    f2 r; r.x = flog2(ar.x); r.y = flog2(ar.y);
                    c2v[kk][j] = r;
                    *(f2*)(sb + (vnp[kk][j] >> 16)) = r;
                }
            }
        }
        __syncthreads();
        // Phase A: slot-indexed marginals; odd-stride sequential b64
        // segment reads, pk adds (generic d+=2 loop — the measured
        // optimum). Last iteration doubles as the final marginal +
        // hard decision.
        #pragma unroll
        for (int k = 0; k < KMAX_; ++k) {
            int s = tid + BS_ * k;
            if (s < K_) {
                int base = (int)(od[k] & 0x1FFFu);
                int dg   = (int)((od[k] >> 13) & 31u);
                f2 mg = lr[k];
                int d = 0;
                for (; d + 1 < dg; d += 2) {
                    mg = mg + s_all2[base + d];        // pk
                    mg = mg + s_all2[base + d + 1];    // pk
                }
                if (d < dg) mg = mg + s_all2[base + d];// pk
                s_all2[CAP_ + s] = mg;
                if (it == NITER_ - 1) {
                    int pv = (int)(od[k] >> 18);
                    out[(size_t)BATCH_ * K_ + b0 * K_ + pv] = (mg.x < 0.0f) ? 1.0f : 0.0f;
                    out[(size_t)BATCH_ * K_ + b1 * K_ + pv] = (mg.y < 0.0f) ? 1.0f : 0.0f;
                }
            }
        }
        __syncthreads();
    }
}

extern "C" void kernel_launch(void* const* d_in, const int* in_sizes, int n_in,
                              void* d_out, int out_size, void* d_ws, size_t ws_size,
                              hipStream_t stream) {
    const int*   bits    = (const int*)  d_in[0];
    const int*   a_idx   = (const int*)  d_in[1];
    // d_in[2] = edge_cn (implicit: contiguous groups of 6) — unused
    const int*   edge_vn = (const int*)  d_in[3];
    const float* pre     = (const float*)d_in[4];
    const float* pim     = (const float*)d_in[5];
    const float* nre     = (const float*)d_in[6];
    const float* nim     = (const float*)d_in[7];
    const float* ebno    = (const float*)d_in[8];

    link_kernel<<<BATCH_ / NCW_, BS_, 0, stream>>>(bits, a_idx, pre, pim, nre, nim,
                                                   ebno, edge_vn, (float*)d_out);
}